// Round 10
// baseline (345.899 us; speedup 1.0000x reference)
//
#include <hip/hip_runtime.h>
#include <hip/hip_bf16.h>

#define N_EMBD 768
#define N_HEADS 12
#define HEAD_DIM 64

typedef __attribute__((ext_vector_type(4))) float f32x4;
typedef __attribute__((ext_vector_type(8))) short s16x8;

__device__ __forceinline__ float bf2f(unsigned short u) {
  union { unsigned int i; float f; } z;
  z.i = ((unsigned int)u) << 16;
  return z.f;
}

__device__ __forceinline__ void gload_lds16(const void* g, void* l) {
  __builtin_amdgcn_global_load_lds(
      (const __attribute__((address_space(1))) void*)g,
      (__attribute__((address_space(3))) void*)l, 16, 0, 0);
}

__device__ __forceinline__ float gelu_f(float x) {
  const float c = 0.7978845608028654f;
  float u = c * (x + 0.044715f * x * x * x);
  float t = 1.0f - 2.0f / (__expf(2.0f * u) + 1.0f);
  return 0.5f * x * (1.0f + t);
}

// ---------------- weight fp32 -> bf16 (all four in one launch) ----------------
__global__ void cvt4_kernel(const float* __restrict__ s0, __hip_bfloat16* d0,
                            const float* __restrict__ s1, __hip_bfloat16* d1,
                            const float* __restrict__ s2, __hip_bfloat16* d2,
                            const float* __restrict__ s3, __hip_bfloat16* d3,
                            int n0, int n1, int n2, int n3) {
  int i = blockIdx.x * 256 + threadIdx.x;
  if (i < n0) { d0[i] = __float2bfloat16(s0[i]); return; }
  i -= n0;
  if (i < n1) { d1[i] = __float2bfloat16(s1[i]); return; }
  i -= n1;
  if (i < n2) { d2[i] = __float2bfloat16(s2[i]); return; }
  i -= n2;
  if (i < n3) d3[i] = __float2bfloat16(s3[i]);
}

// ---------------- fused LayerNorm: fp32 in -> bf16 out ----------------
__global__ __launch_bounds__(256) void ln_kernel(
    const float* __restrict__ x, const float* __restrict__ g,
    const float* __restrict__ b, __hip_bfloat16* __restrict__ out) {
  __shared__ float red[8];
  const int row = blockIdx.x;
  const int tid = threadIdx.x;
  const float* xr = x + (size_t)row * N_EMBD;
  float v0 = xr[tid], v1 = xr[tid + 256], v2 = xr[tid + 512];
  float s = v0 + v1 + v2;
#pragma unroll
  for (int m = 32; m >= 1; m >>= 1) s += __shfl_xor(s, m);
  if ((tid & 63) == 0) red[tid >> 6] = s;
  __syncthreads();
  float mu = (red[0] + red[1] + red[2] + red[3]) * (1.0f / 768.0f);
  float d0 = v0 - mu, d1 = v1 - mu, d2 = v2 - mu;
  float ss = d0 * d0 + d1 * d1 + d2 * d2;
  __syncthreads();
#pragma unroll
  for (int m = 32; m >= 1; m >>= 1) ss += __shfl_xor(ss, m);
  if ((tid & 63) == 0) red[4 + (tid >> 6)] = ss;
  __syncthreads();
  float var = (red[4] + red[5] + red[6] + red[7]) * (1.0f / 768.0f);
  float rstd = rsqrtf(var + 1e-5f);
  __hip_bfloat16* orow = out + (size_t)row * N_EMBD;
  orow[tid]       = __float2bfloat16(d0 * rstd * g[tid]       + b[tid]);
  orow[tid + 256] = __float2bfloat16(d1 * rstd * g[tid + 256] + b[tid + 256]);
  orow[tid + 512] = __float2bfloat16(d2 * rstd * g[tid + 512] + b[tid + 512]);
}

// ---------------- 128x128 GEMM, counted-vmcnt scheme (proj / FC2) ----------------
// vmcnt(0)+raw s_barrier at iteration top (waits only loads issued a full
// iteration earlier); t+1 prefetch issued AFTER the barrier stays in flight
// across the next barrier (no __syncthreads drain).
#define TILE_M 128
#define TILE_N 128
#define TILE_K 32

template <int EPI>
__global__ __launch_bounds__(256) void gemm_bt(
    const __hip_bfloat16* __restrict__ A, const __hip_bfloat16* __restrict__ W,
    const float* __restrict__ bias, const float* __restrict__ resid,
    __hip_bfloat16* __restrict__ outb, float* __restrict__ outf,
    int M, int N, int K) {
  __shared__ __hip_bfloat16 smA[2][TILE_M * TILE_K];
  __shared__ __hip_bfloat16 smB[2][TILE_N * TILE_K];
  const int tid = threadIdx.x;
  const int lane = tid & 63;
  const int wave = tid >> 6;

  const int nbx = gridDim.x;
  const int nwg = nbx * gridDim.y;
  int bid = blockIdx.y * nbx + blockIdx.x;
  if ((nwg & 7) == 0) bid = (bid & 7) * (nwg >> 3) + (bid >> 3);
  const int m0 = (bid / nbx) * TILE_M;
  const int n0 = (bid % nbx) * TILE_N;
  const int wr = wave >> 1, wc = wave & 1;

  f32x4 acc[4][4];
#pragma unroll
  for (int i = 0; i < 4; ++i)
#pragma unroll
    for (int j = 0; j < 4; ++j) acc[i][j] = f32x4{0.f, 0.f, 0.f, 0.f};

  const int ar0 = tid >> 2;
  const int ac0 = (tid & 3) * 8;
  const __hip_bfloat16* Abase0 = A + (size_t)(m0 + ar0) * K + ac0;
  const __hip_bfloat16* Abase1 = A + (size_t)(m0 + 64 + ar0) * K + ac0;
  const __hip_bfloat16* Wbase0 = W + (size_t)(n0 + ar0) * K + ac0;
  const __hip_bfloat16* Wbase1 = W + (size_t)(n0 + 64 + ar0) * K + ac0;

  auto stage = [&](int buf, int k0) {
    gload_lds16(Abase0 + k0, &smA[buf][wave * 512]);
    gload_lds16(Abase1 + k0, &smA[buf][2048 + wave * 512]);
    gload_lds16(Wbase0 + k0, &smB[buf][wave * 512]);
    gload_lds16(Wbase1 + k0, &smB[buf][2048 + wave * 512]);
  };

  const int rA = lane & 15;
  const int ko = (lane >> 4) * 8;
  const int nk = K / TILE_K;

  stage(0, 0);

  int cur = 0;
  for (int t = 0; t < nk; ++t) {
    asm volatile("s_waitcnt vmcnt(0)" ::: "memory");  // tile t landed (issued iter t-1)
    asm volatile("s_barrier" ::: "memory");           // publish t / release t-1 buffer
    if (t + 1 < nk) stage(cur ^ 1, (t + 1) * TILE_K); // stays in flight across next barrier

    s16x8 af[4], bfr[4];
#pragma unroll
    for (int mi = 0; mi < 4; ++mi)
      af[mi] = *(const s16x8*)&smA[cur][(wr * 64 + mi * 16 + rA) * TILE_K + ko];
#pragma unroll
    for (int ni = 0; ni < 4; ++ni)
      bfr[ni] = *(const s16x8*)&smB[cur][(wc * 64 + ni * 16 + rA) * TILE_K + ko];
    __builtin_amdgcn_s_setprio(1);
#pragma unroll
    for (int mi = 0; mi < 4; ++mi)
#pragma unroll
      for (int ni = 0; ni < 4; ++ni)
        acc[mi][ni] = __builtin_amdgcn_mfma_f32_16x16x32_bf16(
            af[mi], bfr[ni], acc[mi][ni], 0, 0, 0);
    __builtin_amdgcn_s_setprio(0);
    cur ^= 1;
  }

  const int crow = (lane >> 4) * 4;
  const int ccol = lane & 15;
#pragma unroll
  for (int mi = 0; mi < 4; ++mi) {
#pragma unroll
    for (int ni = 0; ni < 4; ++ni) {
      const int col = n0 + wc * 64 + ni * 16 + ccol;
      const float bv = bias[col];
#pragma unroll
      for (int j = 0; j < 4; ++j) {
        const int row = m0 + wr * 64 + mi * 16 + crow + j;
        float v = acc[mi][ni][j] + bv;
        const size_t o = (size_t)row * N + col;
        if (EPI == 0) {
          outb[o] = __float2bfloat16(v);
        } else if (EPI == 1) {
          outb[o] = __float2bfloat16(gelu_f(v));
        } else {
          outf[o] = resid[o] + v;
        }
      }
    }
  }
}

// ---------------- 256x256 counted-vmcnt GEMM (QKV / FC) ----------------
// 8 waves (2Mx4N, per-wave 128x64 -> 64 MFMA : 24 b128 reads = MFMA-bound),
// BK=64, 128KB double-buffer, one vmcnt(0)+s_barrier per K-tile at top,
// staging interleaved with the 4 quadrant-phases, setprio around MFMA,
// both-sides XOR swizzle gcol^=(row&7), XCD chunk swizzle.
#define BM3 256
#define BN3 256
#define BK3 64

template <int EPI>
__global__ __launch_bounds__(512, 2) void gemm256b(
    const __hip_bfloat16* __restrict__ A, const __hip_bfloat16* __restrict__ W,
    const float* __restrict__ bias,
    __hip_bfloat16* __restrict__ outb, int M, int N, int K) {
  __shared__ __align__(16) char lds[2][65536];  // [buf][A 32KB | B 32KB]
  const int tid = threadIdx.x;
  const int lane = tid & 63;
  const int wave = tid >> 6;   // 0..7
  const int wr = wave >> 2;    // 0..1 -> row half
  const int wc = wave & 3;     // 0..3 -> col quarter

  const int nbx = gridDim.x;
  const int nwg = nbx * gridDim.y;
  int bid = blockIdx.y * nbx + blockIdx.x;
  if ((nwg & 7) == 0) bid = (bid & 7) * (nwg >> 3) + (bid >> 3);
  const int m0 = (bid / nbx) * BM3;
  const int n0 = (bid % nbx) * BN3;

  f32x4 acc[8][4];
#pragma unroll
  for (int m = 0; m < 8; ++m)
#pragma unroll
    for (int n = 0; n < 4; ++n) acc[m][n] = f32x4{0.f, 0.f, 0.f, 0.f};

  // tile = 256 rows x 64 cols bf16 = 2048 granules of 16B per operand.
  // granule g: row=g>>3, col8=g&7; source col pre-swizzled by row&7;
  // LDS dest linear (granule index = c*512 + wave*64 + lane).
  auto stageA = [&](int buf, int t, int c) {
    const int g = c * 512 + tid;
    const int row = g >> 3;
    const int col = ((g & 7) ^ (row & 7)) * 8;
    gload_lds16(A + (size_t)(m0 + row) * K + t * BK3 + col,
                lds[buf] + (c * 512 + wave * 64) * 16);
  };
  auto stageB = [&](int buf, int t, int c) {
    const int g = c * 512 + tid;
    const int row = g >> 3;
    const int col = ((g & 7) ^ (row & 7)) * 8;
    gload_lds16(W + (size_t)(n0 + row) * K + t * BK3 + col,
                lds[buf] + 32768 + (c * 512 + wave * 64) * 16);
  };

  const int fr = lane & 15;   // fragment row
  const int fq = lane >> 4;   // k-quarter
  const int nk = K / BK3;

#pragma unroll
  for (int c = 0; c < 4; ++c) { stageA(0, 0, c); stageB(0, 0, c); }

  int cur = 0;
  for (int t = 0; t < nk; ++t) {
    asm volatile("s_waitcnt vmcnt(0)" ::: "memory");  // tile t landed
    asm volatile("s_barrier" ::: "memory");           // publish t / release t-1
    const char* Ab = lds[cur];
    const char* Bb = lds[cur] + 32768;
    const bool pre = (t + 1 < nk);

    if (pre) { stageA(cur ^ 1, t + 1, 0); stageB(cur ^ 1, t + 1, 0); }

    // B fragments: all 4 n-frags x 2 k-halves, cached across phases
    s16x8 bfr[4][2];
#pragma unroll
    for (int n = 0; n < 4; ++n)
#pragma unroll
      for (int kh = 0; kh < 2; ++kh) {
        const int row = wc * 64 + n * 16 + fr;
        const int gc = (kh * 4 + fq) ^ (row & 7);
        bfr[n][kh] = *(const s16x8*)(Bb + row * 128 + gc * 16);
      }

#pragma unroll
    for (int p = 0; p < 4; ++p) {
      if (pre && p > 0) { stageA(cur ^ 1, t + 1, p); stageB(cur ^ 1, t + 1, p); }
      s16x8 af[2][2];
#pragma unroll
      for (int i = 0; i < 2; ++i)
#pragma unroll
        for (int kh = 0; kh < 2; ++kh) {
          const int row = wr * 128 + (2 * p + i) * 16 + fr;
          const int gc = (kh * 4 + fq) ^ (row & 7);
          af[i][kh] = *(const s16x8*)(Ab + row * 128 + gc * 16);
        }
      __builtin_amdgcn_s_setprio(1);
#pragma unroll
      for (int i = 0; i < 2; ++i)
#pragma unroll
        for (int n = 0; n < 4; ++n)
#pragma unroll
          for (int kh = 0; kh < 2; ++kh)
            acc[2 * p + i][n] = __builtin_amdgcn_mfma_f32_16x16x32_bf16(
                af[i][kh], bfr[n][kh], acc[2 * p + i][n], 0, 0, 0);
      __builtin_amdgcn_s_setprio(0);
    }
    cur ^= 1;
  }

  const int crow = fq * 4;
#pragma unroll
  for (int m = 0; m < 8; ++m) {
#pragma unroll
    for (int n = 0; n < 4; ++n) {
      const int col = n0 + wc * 64 + n * 16 + fr;
      const float bv = bias[col];
#pragma unroll
      for (int j = 0; j < 4; ++j) {
        const int row = m0 + wr * 128 + m * 16 + crow + j;
        float v = acc[m][n][j] + bv;
        const size_t o = (size_t)row * N + col;
        if (EPI == 0) outb[o] = __float2bfloat16(v);
        else outb[o] = __float2bfloat16(gelu_f(v));
      }
    }
  }
}

// ---------------- MFMA causal flash attention (R8-verified, 131us) ----------------
#define AP 72

__global__ __launch_bounds__(256) void attn_mfma(
    const __hip_bfloat16* __restrict__ qkv, __hip_bfloat16* __restrict__ y,
    int T) {
  __shared__ __hip_bfloat16 ks[64 * AP];
  __shared__ __hip_bfloat16 vt[64 * AP];
  __shared__ __hip_bfloat16 ps[4][16 * AP];
  const int tid = threadIdx.x;
  const int lane = tid & 63;
  const int wave = tid >> 6;
  const int b = blockIdx.y / N_HEADS, h = blockIdx.y % N_HEADS;
  const int nq = T / 64;
  const int qa0 = blockIdx.x * 64;
  const int qb0 = (nq - 1 - blockIdx.x) * 64;
  const size_t ldq = 3 * N_EMBD;
  const __hip_bfloat16* qb_ = qkv + (size_t)b * T * ldq + h * HEAD_DIM;
  const __hip_bfloat16* kb = qb_ + N_EMBD;
  const __hip_bfloat16* vb = qb_ + 2 * N_EMBD;

  const int fr = lane & 15;
  const int fo = (lane >> 4) * 8;
  const int crow = (lane >> 4) * 4;

  const float qs = 0.125f * 1.44269504f;
  auto loadq = [&](int qrow, int o) -> s16x8 {
    s16x8 v = *(const s16x8*)(qb_ + (size_t)qrow * ldq + o);
    s16x8 r;
#pragma unroll
    for (int i = 0; i < 8; ++i) {
      float f = bf2f((unsigned short)v[i]) * qs;
      __hip_bfloat16 hb = __float2bfloat16(f);
      r[i] = *reinterpret_cast<short*>(&hb);
    }
    return r;
  };
  s16x8 qfa0 = loadq(qa0 + wave * 16 + fr, fo);
  s16x8 qfa1 = loadq(qa0 + wave * 16 + fr, fo + 32);
  s16x8 qfb0 = loadq(qb0 + wave * 16 + fr, fo);
  s16x8 qfb1 = loadq(qb0 + wave * 16 + fr, fo + 32);

  f32x4 oa[4], ob[4];
  float ma[4], la[4], mb[4], lb_[4];
#pragma unroll
  for (int j = 0; j < 4; ++j) {
    oa[j] = f32x4{0.f, 0.f, 0.f, 0.f};
    ob[j] = f32x4{0.f, 0.f, 0.f, 0.f};
    ma[j] = -1e30f; la[j] = 0.f; mb[j] = -1e30f; lb_[j] = 0.f;
  }

  auto process = [&](const s16x8& q0f, const s16x8& q1f, f32x4 (&o)[4],
                     float (&m_)[4], float (&l_)[4], int tq0, bool diag,
                     int kt) {
    f32x4 sv[4];
#pragma unroll
    for (int sub = 0; sub < 4; ++sub) {
      s16x8 b0 = *(const s16x8*)&ks[(sub * 16 + fr) * AP + fo];
      s16x8 b1 = *(const s16x8*)&ks[(sub * 16 + fr) * AP + 32 + fo];
      f32x4 acc = f32x4{0.f, 0.f, 0.f, 0.f};
      acc = __builtin_amdgcn_mfma_f32_16x16x32_bf16(q0f, b0, acc, 0, 0, 0);
      acc = __builtin_amdgcn_mfma_f32_16x16x32_bf16(q1f, b1, acc, 0, 0, 0);
      sv[sub] = acc;
    }
    if (diag) {
      const int wq0 = tq0 + wave * 16;
#pragma unroll
      for (int sub = 0; sub < 4; ++sub) {
        const int key = kt + sub * 16 + fr;
#pragma unroll
        for (int j = 0; j < 4; ++j)
          if (key > wq0 + crow + j) sv[sub][j] = -1e30f;
      }
    }
    float corr[4];
    bool anyresc = false;
#pragma unroll
    for (int j = 0; j < 4; ++j) {
      float t = fmaxf(fmaxf(sv[0][j], sv[1][j]), fmaxf(sv[2][j], sv[3][j]));
#pragma unroll
      for (int msk = 1; msk <= 8; msk <<= 1) t = fmaxf(t, __shfl_xor(t, msk));
      const bool resc = t > m_[j] + 8.0f;
      corr[j] = resc ? exp2f(m_[j] - t) : 1.0f;
      if (resc) m_[j] = t;
      anyresc = anyresc || resc;
    }
    float rs[4] = {0.f, 0.f, 0.f, 0.f};
#pragma unroll
    for (int sub = 0; sub < 4; ++sub) {
#pragma unroll
      for (int j = 0; j < 4; ++j) {
        float p = exp2f(sv[sub][j] - m_[j]);
        rs[j] += p;
        ps[wave][(crow + j) * AP + sub * 16 + fr] = __float2bfloat16(p);
      }
    }
#pragma unroll
    for (int j = 0; j < 4; ++j) {
#pragma unroll
      for (int msk = 1; msk <= 8; msk <<= 1) rs[j] += __shfl_xor(rs[j], msk);
      l_[j] = l_[j] * corr[j] + rs[j];
    }
    if (__any(anyresc)) {
#pragma unroll
      for (int ds = 0; ds < 4; ++ds)
#pragma unroll
        for (int j = 0; j < 4; ++j) o[ds][j] *= corr[j];
    }
    s16x8 pf0 = *(const s16x8*)&ps[wave][fr * AP + fo];
    s16x8 pf1 = *(const s16x8*)&ps[wave][fr * AP + 32 + fo];
#pragma unroll
    for (int ds = 0; ds < 4; ++ds) {
      s16x8 v0 = *(const s16x8*)&vt[(ds * 16 + fr) * AP + fo];
      s16x8 v1 = *(const s16x8*)&vt[(ds * 16 + fr) * AP + 32 + fo];
      o[ds] = __builtin_amdgcn_mfma_f32_16x16x32_bf16(pf0, v0, o[ds], 0, 0, 0);
      o[ds] = __builtin_amdgcn_mfma_f32_16x16x32_bf16(pf1, v1, o[ds], 0, 0, 0);
    }
  };

  for (int kt = 0; kt <= qb0; kt += 64) {
    __syncthreads();
#pragma unroll
    for (int j = 0; j < 2; ++j) {
      int c = j * 256 + tid;
      int key = c >> 3, d0 = (c & 7) * 8;
      s16x8 kv = *(const s16x8*)(kb + (size_t)(kt + key) * ldq + d0);
      *(s16x8*)&ks[key * AP + d0] = kv;
    }
#pragma unroll
    for (int j = 0; j < 2; ++j) {
      int d0 = (wave * 2 + j) * 8;
      s16x8 vv = *(const s16x8*)(vb + (size_t)(kt + lane) * ldq + d0);
#pragma unroll
      for (int i = 0; i < 8; ++i)
        vt[(d0 + i) * AP + lane] = ((const __hip_bfloat16*)&vv)[i];
    }
    __syncthreads();

    if (kt <= qa0) process(qfa0, qfa1, oa, ma, la, qa0, kt == qa0, kt);
    process(qfb0, qfb1, ob, mb, lb_, qb0, kt == qb0, kt);
  }

#pragma unroll
  for (int j = 0; j < 4; ++j) {
    const float inva = 1.0f / la[j];
    const float invb = 1.0f / lb_[j];
    __hip_bfloat16* ya =
        y + (size_t)(b * T + qa0 + wave * 16 + crow + j) * N_EMBD + h * HEAD_DIM;
    __hip_bfloat16* yb =
        y + (size_t)(b * T + qb0 + wave * 16 + crow + j) * N_EMBD + h * HEAD_DIM;
#pragma unroll
    for (int ds = 0; ds < 4; ++ds) {
      ya[ds * 16 + fr] = __float2bfloat16(oa[ds][j] * inva);
      yb[ds * 16 + fr] = __float2bfloat16(ob[ds][j] * invb);
    }
  }
}

// ---------------- launch ----------------
extern "C" void kernel_launch(void* const* d_in, const int* in_sizes, int n_in,
                              void* d_out, int out_size, void* d_ws,
                              size_t ws_size, hipStream_t stream) {
  const int B = 4, T = 2048, C = N_EMBD;
  const int M = B * T;  // 8192

  const float* x      = (const float*)d_in[0];
  const float* ln1_g  = (const float*)d_in[1];
  const float* ln1_b  = (const float*)d_in[2];
  const float* attn_w = (const float*)d_in[3];
  const float* attn_b = (const float*)d_in[4];
  const float* proj_w = (const float*)d_in[5];
  const float* proj_b = (const float*)d_in[6];
  const float* ln2_g  = (const float*)d_in[7];
  const float* ln2_b  = (const float*)d_in[8];
  const float* fc_w   = (const float*)d_in[9];
  const float* fc_b   = (const float*)d_in[10];
  const float* fc2_w  = (const float*)d_in[11];
  const float* fc2_b  = (const float*)d_in[12];
  float* out = (float*)d_out;

  char* p = (char*)d_ws;
  size_t off = 0;
  auto take = [&](size_t bytes) -> void* {
    void* q = p + off;
    off += (bytes + 1023) & ~(size_t)1023;
    return q;
  };

  __hip_bfloat16* wqkv  = (__hip_bfloat16*)take((size_t)3 * C * C * 2);
  __hip_bfloat16* wproj = (__hip_bfloat16*)take((size_t)C * C * 2);
  __hip_bfloat16* wfc   = (__hip_bfloat16*)take((size_t)4 * C * C * 2);
  __hip_bfloat16* wfc2  = (__hip_bfloat16*)take((size_t)4 * C * C * 2);
  __hip_bfloat16* hbuf  = (__hip_bfloat16*)take((size_t)M * C * 2);
  __hip_bfloat16* big   = (__hip_bfloat16*)take((size_t)M * 4 * C * 2);
  __hip_bfloat16* ybuf  = (__hip_bfloat16*)take((size_t)M * C * 2);
  float*          x1    = (float*)take((size_t)M * C * 4);

  {
    const int n0 = 3 * C * C, n1 = C * C, n2 = 4 * C * C, n3 = 4 * C * C;
    const int ntot = n0 + n1 + n2 + n3;
    cvt4_kernel<<<(ntot + 255) / 256, 256, 0, stream>>>(
        attn_w, wqkv, proj_w, wproj, fc_w, wfc, fc2_w, wfc2, n0, n1, n2, n3);
  }

  ln_kernel<<<M, 256, 0, stream>>>(x, ln1_g, ln1_b, hbuf);
  // QKV: [8192,2304], 256^2 counted pipeline
  gemm256b<0><<<dim3(3 * C / BN3, M / BM3), 512, 0, stream>>>(
      hbuf, wqkv, attn_b, big, M, 3 * C, C);
  attn_mfma<<<dim3(T / 128, B * N_HEADS), 256, 0, stream>>>(big, ybuf, T);
  // proj: 128^2 counted
  gemm_bt<2><<<dim3(C / TILE_N, M / TILE_M), 256, 0, stream>>>(
      ybuf, wproj, proj_b, x, nullptr, x1, M, C, C);
  ln_kernel<<<M, 256, 0, stream>>>(x1, ln2_g, ln2_b, hbuf);
  // FC: [8192,3072] gelu, 256^2 counted pipeline
  gemm256b<1><<<dim3(4 * C / BN3, M / BM3), 512, 0, stream>>>(
      hbuf, wfc, fc_b, big, M, 4 * C, C);
  // FC2: [8192,768] resid fp32, K=3072, 128^2 counted
  gemm_bt<2><<<dim3(C / TILE_N, M / TILE_M), 256, 0, stream>>>(
      big, wfc2, fc2_b, x1, nullptr, out, M, C, 4 * C);
}

// Round 11
// 305.606 us; speedup vs baseline: 1.1318x; 1.1318x over previous
//
#include <hip/hip_runtime.h>
#include <hip/hip_bf16.h>

#define N_EMBD 768
#define N_HEADS 12
#define HEAD_DIM 64

typedef __attribute__((ext_vector_type(4))) float f32x4;
typedef __attribute__((ext_vector_type(8))) short s16x8;

__device__ __forceinline__ float bf2f(unsigned short u) {
  union { unsigned int i; float f; } z;
  z.i = ((unsigned int)u) << 16;
  return z.f;
}

__device__ __forceinline__ void gload_lds16(const void* g, void* l) {
  __builtin_amdgcn_global_load_lds(
      (const __attribute__((address_space(1))) void*)g,
      (__attribute__((address_space(3))) void*)l, 16, 0, 0);
}

__device__ __forceinline__ float gelu_f(float x) {
  const float c = 0.7978845608028654f;
  float u = c * (x + 0.044715f * x * x * x);
  float t = 1.0f - 2.0f / (__expf(2.0f * u) + 1.0f);
  return 0.5f * x * (1.0f + t);
}

// ---------------- weight fp32 -> bf16 (all four in one launch) ----------------
__global__ void cvt4_kernel(const float* __restrict__ s0, __hip_bfloat16* d0,
                            const float* __restrict__ s1, __hip_bfloat16* d1,
                            const float* __restrict__ s2, __hip_bfloat16* d2,
                            const float* __restrict__ s3, __hip_bfloat16* d3,
                            int n0, int n1, int n2, int n3) {
  int i = blockIdx.x * 256 + threadIdx.x;
  if (i < n0) { d0[i] = __float2bfloat16(s0[i]); return; }
  i -= n0;
  if (i < n1) { d1[i] = __float2bfloat16(s1[i]); return; }
  i -= n1;
  if (i < n2) { d2[i] = __float2bfloat16(s2[i]); return; }
  i -= n2;
  if (i < n3) d3[i] = __float2bfloat16(s3[i]);
}

// ---------------- fused LayerNorm: fp32 in -> bf16 out ----------------
__global__ __launch_bounds__(256) void ln_kernel(
    const float* __restrict__ x, const float* __restrict__ g,
    const float* __restrict__ b, __hip_bfloat16* __restrict__ out) {
  __shared__ float red[8];
  const int row = blockIdx.x;
  const int tid = threadIdx.x;
  const float* xr = x + (size_t)row * N_EMBD;
  float v0 = xr[tid], v1 = xr[tid + 256], v2 = xr[tid + 512];
  float s = v0 + v1 + v2;
#pragma unroll
  for (int m = 32; m >= 1; m >>= 1) s += __shfl_xor(s, m);
  if ((tid & 63) == 0) red[tid >> 6] = s;
  __syncthreads();
  float mu = (red[0] + red[1] + red[2] + red[3]) * (1.0f / 768.0f);
  float d0 = v0 - mu, d1 = v1 - mu, d2 = v2 - mu;
  float ss = d0 * d0 + d1 * d1 + d2 * d2;
  __syncthreads();
#pragma unroll
  for (int m = 32; m >= 1; m >>= 1) ss += __shfl_xor(ss, m);
  if ((tid & 63) == 0) red[4 + (tid >> 6)] = ss;
  __syncthreads();
  float var = (red[4] + red[5] + red[6] + red[7]) * (1.0f / 768.0f);
  float rstd = rsqrtf(var + 1e-5f);
  __hip_bfloat16* orow = out + (size_t)row * N_EMBD;
  orow[tid]       = __float2bfloat16(d0 * rstd * g[tid]       + b[tid]);
  orow[tid + 256] = __float2bfloat16(d1 * rstd * g[tid + 256] + b[tid + 256]);
  orow[tid + 512] = __float2bfloat16(d2 * rstd * g[tid + 512] + b[tid + 512]);
}

// ---------------- 128x128 GEMM, counted-vmcnt scheme (proj / FC2) ----------------
#define TILE_M 128
#define TILE_N 128
#define TILE_K 32

template <int EPI>
__global__ __launch_bounds__(256) void gemm_bt(
    const __hip_bfloat16* __restrict__ A, const __hip_bfloat16* __restrict__ W,
    const float* __restrict__ bias, const float* __restrict__ resid,
    __hip_bfloat16* __restrict__ outb, float* __restrict__ outf,
    int M, int N, int K) {
  __shared__ __hip_bfloat16 smA[2][TILE_M * TILE_K];
  __shared__ __hip_bfloat16 smB[2][TILE_N * TILE_K];
  const int tid = threadIdx.x;
  const int lane = tid & 63;
  const int wave = tid >> 6;

  const int nbx = gridDim.x;
  const int nwg = nbx * gridDim.y;
  int bid = blockIdx.y * nbx + blockIdx.x;
  if ((nwg & 7) == 0) bid = (bid & 7) * (nwg >> 3) + (bid >> 3);
  const int m0 = (bid / nbx) * TILE_M;
  const int n0 = (bid % nbx) * TILE_N;
  const int wr = wave >> 1, wc = wave & 1;

  f32x4 acc[4][4];
#pragma unroll
  for (int i = 0; i < 4; ++i)
#pragma unroll
    for (int j = 0; j < 4; ++j) acc[i][j] = f32x4{0.f, 0.f, 0.f, 0.f};

  const int ar0 = tid >> 2;
  const int ac0 = (tid & 3) * 8;
  const __hip_bfloat16* Abase0 = A + (size_t)(m0 + ar0) * K + ac0;
  const __hip_bfloat16* Abase1 = A + (size_t)(m0 + 64 + ar0) * K + ac0;
  const __hip_bfloat16* Wbase0 = W + (size_t)(n0 + ar0) * K + ac0;
  const __hip_bfloat16* Wbase1 = W + (size_t)(n0 + 64 + ar0) * K + ac0;

  auto stage = [&](int buf, int k0) {
    gload_lds16(Abase0 + k0, &smA[buf][wave * 512]);
    gload_lds16(Abase1 + k0, &smA[buf][2048 + wave * 512]);
    gload_lds16(Wbase0 + k0, &smB[buf][wave * 512]);
    gload_lds16(Wbase1 + k0, &smB[buf][2048 + wave * 512]);
  };

  const int rA = lane & 15;
  const int ko = (lane >> 4) * 8;
  const int nk = K / TILE_K;

  stage(0, 0);

  int cur = 0;
  for (int t = 0; t < nk; ++t) {
    asm volatile("s_waitcnt vmcnt(0)" ::: "memory");
    asm volatile("s_barrier" ::: "memory");
    if (t + 1 < nk) stage(cur ^ 1, (t + 1) * TILE_K);

    s16x8 af[4], bfr[4];
#pragma unroll
    for (int mi = 0; mi < 4; ++mi)
      af[mi] = *(const s16x8*)&smA[cur][(wr * 64 + mi * 16 + rA) * TILE_K + ko];
#pragma unroll
    for (int ni = 0; ni < 4; ++ni)
      bfr[ni] = *(const s16x8*)&smB[cur][(wc * 64 + ni * 16 + rA) * TILE_K + ko];
    __builtin_amdgcn_s_setprio(1);
#pragma unroll
    for (int mi = 0; mi < 4; ++mi)
#pragma unroll
      for (int ni = 0; ni < 4; ++ni)
        acc[mi][ni] = __builtin_amdgcn_mfma_f32_16x16x32_bf16(
            af[mi], bfr[ni], acc[mi][ni], 0, 0, 0);
    __builtin_amdgcn_s_setprio(0);
    cur ^= 1;
  }

  const int crow = (lane >> 4) * 4;
  const int ccol = lane & 15;
#pragma unroll
  for (int mi = 0; mi < 4; ++mi) {
#pragma unroll
    for (int ni = 0; ni < 4; ++ni) {
      const int col = n0 + wc * 64 + ni * 16 + ccol;
      const float bv = bias[col];
#pragma unroll
      for (int j = 0; j < 4; ++j) {
        const int row = m0 + wr * 64 + mi * 16 + crow + j;
        float v = acc[mi][ni][j] + bv;
        const size_t o = (size_t)row * N + col;
        if (EPI == 0) {
          outb[o] = __float2bfloat16(v);
        } else if (EPI == 1) {
          outb[o] = __float2bfloat16(gelu_f(v));
        } else {
          outf[o] = resid[o] + v;
        }
      }
    }
  }
}

// ---------------- 256x256 counted-vmcnt GEMM (QKV / FC) ----------------
#define BM3 256
#define BN3 256
#define BK3 64

template <int EPI>
__global__ __launch_bounds__(512, 2) void gemm256b(
    const __hip_bfloat16* __restrict__ A, const __hip_bfloat16* __restrict__ W,
    const float* __restrict__ bias,
    __hip_bfloat16* __restrict__ outb, int M, int N, int K) {
  __shared__ __align__(16) char lds[2][65536];
  const int tid = threadIdx.x;
  const int lane = tid & 63;
  const int wave = tid >> 6;
  const int wr = wave >> 2;
  const int wc = wave & 3;

  const int nbx = gridDim.x;
  const int nwg = nbx * gridDim.y;
  int bid = blockIdx.y * nbx + blockIdx.x;
  if ((nwg & 7) == 0) bid = (bid & 7) * (nwg >> 3) + (bid >> 3);
  const int m0 = (bid / nbx) * BM3;
  const int n0 = (bid % nbx) * BN3;

  f32x4 acc[8][4];
#pragma unroll
  for (int m = 0; m < 8; ++m)
#pragma unroll
    for (int n = 0; n < 4; ++n) acc[m][n] = f32x4{0.f, 0.f, 0.f, 0.f};

  auto stageA = [&](int buf, int t, int c) {
    const int g = c * 512 + tid;
    const int row = g >> 3;
    const int col = ((g & 7) ^ (row & 7)) * 8;
    gload_lds16(A + (size_t)(m0 + row) * K + t * BK3 + col,
                lds[buf] + (c * 512 + wave * 64) * 16);
  };
  auto stageB = [&](int buf, int t, int c) {
    const int g = c * 512 + tid;
    const int row = g >> 3;
    const int col = ((g & 7) ^ (row & 7)) * 8;
    gload_lds16(W + (size_t)(n0 + row) * K + t * BK3 + col,
                lds[buf] + 32768 + (c * 512 + wave * 64) * 16);
  };

  const int fr = lane & 15;
  const int fq = lane >> 4;
  const int nk = K / BK3;

#pragma unroll
  for (int c = 0; c < 4; ++c) { stageA(0, 0, c); stageB(0, 0, c); }

  int cur = 0;
  for (int t = 0; t < nk; ++t) {
    asm volatile("s_waitcnt vmcnt(0)" ::: "memory");
    asm volatile("s_barrier" ::: "memory");
    const char* Ab = lds[cur];
    const char* Bb = lds[cur] + 32768;
    const bool pre = (t + 1 < nk);

    if (pre) { stageA(cur ^ 1, t + 1, 0); stageB(cur ^ 1, t + 1, 0); }

    s16x8 bfr[4][2];
#pragma unroll
    for (int n = 0; n < 4; ++n)
#pragma unroll
      for (int kh = 0; kh < 2; ++kh) {
        const int row = wc * 64 + n * 16 + fr;
        const int gc = (kh * 4 + fq) ^ (row & 7);
        bfr[n][kh] = *(const s16x8*)(Bb + row * 128 + gc * 16);
      }

#pragma unroll
    for (int p = 0; p < 4; ++p) {
      if (pre && p > 0) { stageA(cur ^ 1, t + 1, p); stageB(cur ^ 1, t + 1, p); }
      s16x8 af[2][2];
#pragma unroll
      for (int i = 0; i < 2; ++i)
#pragma unroll
        for (int kh = 0; kh < 2; ++kh) {
          const int row = wr * 128 + (2 * p + i) * 16 + fr;
          const int gc = (kh * 4 + fq) ^ (row & 7);
          af[i][kh] = *(const s16x8*)(Ab + row * 128 + gc * 16);
        }
      __builtin_amdgcn_s_setprio(1);
#pragma unroll
      for (int i = 0; i < 2; ++i)
#pragma unroll
        for (int n = 0; n < 4; ++n)
#pragma unroll
          for (int kh = 0; kh < 2; ++kh)
            acc[2 * p + i][n] = __builtin_amdgcn_mfma_f32_16x16x32_bf16(
                af[i][kh], bfr[n][kh], acc[2 * p + i][n], 0, 0, 0);
      __builtin_amdgcn_s_setprio(0);
    }
    cur ^= 1;
  }

  const int crow = fq * 4;
#pragma unroll
  for (int m = 0; m < 8; ++m) {
#pragma unroll
    for (int n = 0; n < 4; ++n) {
      const int col = n0 + wc * 64 + n * 16 + fr;
      const float bv = bias[col];
#pragma unroll
      for (int j = 0; j < 4; ++j) {
        const int row = m0 + wr * 128 + m * 16 + crow + j;
        float v = acc[m][n][j] + bv;
        const size_t o = (size_t)row * N + col;
        if (EPI == 0) outb[o] = __float2bfloat16(v);
        else outb[o] = __float2bfloat16(gelu_f(v));
      }
    }
  }
}

// ---------------- MFMA causal flash attention, v3 ----------------
// Paired q-tiles (balance) + reg-prefetch staging (loads for tile t+1 fly
// under process of t; KVBLK=64 so LDS stays 27.6KB) + SWAPPED QK^T
// (mfma(K,Q)): lane owns ONE q-row (q=fr) x 16 keys -> softmax row-reduce
// is 15 local ops + 2 shfl (was 4 rows x 8 shfl). P store / PV unchanged.
#define AP 72

__global__ __launch_bounds__(256) void attn_mfma(
    const __hip_bfloat16* __restrict__ qkv, __hip_bfloat16* __restrict__ y,
    int T) {
  __shared__ __hip_bfloat16 ks[64 * AP];      // [key][d]
  __shared__ __hip_bfloat16 vt[64 * AP];      // [d][key]
  __shared__ __hip_bfloat16 ps[4][16 * AP];   // per-wave P [q][key]
  const int tid = threadIdx.x;
  const int lane = tid & 63;
  const int wave = tid >> 6;
  const int b = blockIdx.y / N_HEADS, h = blockIdx.y % N_HEADS;
  const int nq = T / 64;
  const int qa0 = blockIdx.x * 64;             // early tile
  const int qb0 = (nq - 1 - blockIdx.x) * 64;  // late tile
  const size_t ldq = 3 * N_EMBD;
  const __hip_bfloat16* qb_ = qkv + (size_t)b * T * ldq + h * HEAD_DIM;
  const __hip_bfloat16* kb = qb_ + N_EMBD;
  const __hip_bfloat16* vb = qb_ + 2 * N_EMBD;

  const int fr = lane & 15;          // q-row owned by this lane (swapped QK)
  const int fo = (lane >> 4) * 8;    // fragment k-offset
  const int crow = (lane >> 4) * 4;  // C/D row base (= key sub-block here)

  // prescale Q by 1/sqrt(D) * log2(e) so softmax uses native exp2
  const float qs = 0.125f * 1.44269504f;
  auto loadq = [&](int qrow, int o) -> s16x8 {
    s16x8 v = *(const s16x8*)(qb_ + (size_t)qrow * ldq + o);
    s16x8 r;
#pragma unroll
    for (int i = 0; i < 8; ++i) {
      float f = bf2f((unsigned short)v[i]) * qs;
      __hip_bfloat16 hb = __float2bfloat16(f);
      r[i] = *reinterpret_cast<short*>(&hb);
    }
    return r;
  };
  s16x8 qfa0 = loadq(qa0 + wave * 16 + fr, fo);
  s16x8 qfa1 = loadq(qa0 + wave * 16 + fr, fo + 32);
  s16x8 qfb0 = loadq(qb0 + wave * 16 + fr, fo);
  s16x8 qfb1 = loadq(qb0 + wave * 16 + fr, fo + 32);

  f32x4 oa[4], ob[4];
#pragma unroll
  for (int j = 0; j < 4; ++j) {
    oa[j] = f32x4{0.f, 0.f, 0.f, 0.f};
    ob[j] = f32x4{0.f, 0.f, 0.f, 0.f};
  }
  float m_a = -1e30f, l_a = 0.f, m_b = -1e30f, l_b = 0.f;

  // ---- reg-prefetch staging (KVBLK=64) ----
  // K: thread covers rows tid>>3 and 32+(tid>>3), col (tid&7)*8 (16B each)
  // V: thread covers keys 2*(lane&31), +1 at d-range wave*16 + (lane>>5)*8
  s16x8 kr0, kr1, vr0, vr1;
  const int krow0 = tid >> 3;
  const int kcol = (tid & 7) * 8;
  const int vkey = 2 * (lane & 31);
  const int vd0 = wave * 16 + (lane >> 5) * 8;

  auto loadKV = [&](int kt) {
    kr0 = *(const s16x8*)(kb + (size_t)(kt + krow0) * ldq + kcol);
    kr1 = *(const s16x8*)(kb + (size_t)(kt + 32 + krow0) * ldq + kcol);
    vr0 = *(const s16x8*)(vb + (size_t)(kt + vkey) * ldq + vd0);
    vr1 = *(const s16x8*)(vb + (size_t)(kt + vkey + 1) * ldq + vd0);
  };
  auto writeKV = [&]() {
    *(s16x8*)&ks[krow0 * AP + kcol] = kr0;
    *(s16x8*)&ks[(32 + krow0) * AP + kcol] = kr1;
#pragma unroll
    for (int i = 0; i < 8; ++i) {
      unsigned u = (unsigned short)vr0[i] | ((unsigned)(unsigned short)vr1[i] << 16);
      *(unsigned*)&vt[(vd0 + i) * AP + vkey] = u;
    }
  };

  auto process = [&](const s16x8& q0f, const s16x8& q1f, f32x4 (&o)[4],
                     float& m_, float& l_, int tq0, bool diag, int kt) {
    // swapped QK^T: S^T block. lane (fr,fq) holds S[key=s*16+crow+j][q=fr]
    f32x4 sv[4];
#pragma unroll
    for (int sub = 0; sub < 4; ++sub) {
      s16x8 k0 = *(const s16x8*)&ks[(sub * 16 + fr) * AP + fo];
      s16x8 k1 = *(const s16x8*)&ks[(sub * 16 + fr) * AP + 32 + fo];
      f32x4 acc = f32x4{0.f, 0.f, 0.f, 0.f};
      acc = __builtin_amdgcn_mfma_f32_16x16x32_bf16(k0, q0f, acc, 0, 0, 0);
      acc = __builtin_amdgcn_mfma_f32_16x16x32_bf16(k1, q1f, acc, 0, 0, 0);
      sv[sub] = acc;
    }
    const int qg = tq0 + wave * 16 + fr;  // this lane's q row
    if (diag) {
#pragma unroll
      for (int sub = 0; sub < 4; ++sub)
#pragma unroll
        for (int j = 0; j < 4; ++j)
          if (kt + sub * 16 + crow + j > qg) sv[sub][j] = -1e30f;
    }
    // row max: 15 local + 2 shfl
    float t = fmaxf(fmaxf(sv[0][0], sv[0][1]), fmaxf(sv[0][2], sv[0][3]));
#pragma unroll
    for (int sub = 1; sub < 4; ++sub)
      t = fmaxf(t, fmaxf(fmaxf(sv[sub][0], sv[sub][1]),
                         fmaxf(sv[sub][2], sv[sub][3])));
    t = fmaxf(t, __shfl_xor(t, 16));
    t = fmaxf(t, __shfl_xor(t, 32));
    const bool resc = t > m_ + 8.0f;  // T13 defer-max
    const float corr = resc ? exp2f(m_ - t) : 1.0f;
    if (resc) m_ = t;
    float rs = 0.f;
#pragma unroll
    for (int sub = 0; sub < 4; ++sub) {
#pragma unroll
      for (int j = 0; j < 4; ++j) {
        float p = exp2f(sv[sub][j] - m_);
        rs += p;
        ps[wave][fr * AP + sub * 16 + crow + j] = __float2bfloat16(p);
      }
    }
    rs += __shfl_xor(rs, 16);
    rs += __shfl_xor(rs, 32);
    l_ = l_ * corr + rs;
    if (__any(resc)) {
#pragma unroll
      for (int j = 0; j < 4; ++j) {
        const float cj = __shfl(corr, (lane & 0x30) | (crow + j));
#pragma unroll
        for (int ds = 0; ds < 4; ++ds) o[ds][j] *= cj;
      }
    }
    // PV (unchanged): A = P row fr, B = V^T rows
    s16x8 pf0 = *(const s16x8*)&ps[wave][fr * AP + fo];
    s16x8 pf1 = *(const s16x8*)&ps[wave][fr * AP + 32 + fo];
#pragma unroll
    for (int ds = 0; ds < 4; ++ds) {
      s16x8 v0 = *(const s16x8*)&vt[(ds * 16 + fr) * AP + fo];
      s16x8 v1 = *(const s16x8*)&vt[(ds * 16 + fr) * AP + 32 + fo];
      o[ds] = __builtin_amdgcn_mfma_f32_16x16x32_bf16(pf0, v0, o[ds], 0, 0, 0);
      o[ds] = __builtin_amdgcn_mfma_f32_16x16x32_bf16(pf1, v1, o[ds], 0, 0, 0);
    }
  };

  loadKV(0);
  for (int kt = 0; kt <= qb0; kt += 64) {
    __syncthreads();                       // previous tile's readers done
    writeKV();
    __syncthreads();                       // tile kt published
    if (kt + 64 <= qb0) loadKV(kt + 64);   // flies under process
    if (kt <= qa0) process(qfa0, qfa1, oa, m_a, l_a, qa0, kt == qa0, kt);
    process(qfb0, qfb1, ob, m_b, l_b, qb0, kt == qb0, kt);
  }

#pragma unroll
  for (int j = 0; j < 4; ++j) {
    const float la_j = __shfl(l_a, (lane & 0x30) | (crow + j));
    const float lb_j = __shfl(l_b, (lane & 0x30) | (crow + j));
    const float inva = 1.0f / la_j;
    const float invb = 1.0f / lb_j;
    __hip_bfloat16* ya =
        y + (size_t)(b * T + qa0 + wave * 16 + crow + j) * N_EMBD + h * HEAD_DIM;
    __hip_bfloat16* yb =
        y + (size_t)(b * T + qb0 + wave * 16 + crow + j) * N_EMBD + h * HEAD_DIM;
#pragma unroll
    for (int ds = 0; ds < 4; ++ds) {
      ya[ds * 16 + fr] = __float2bfloat16(oa[ds][j] * inva);
      yb[ds * 16 + fr] = __float2bfloat16(ob[ds][j] * invb);
    }
  }
}

// ---------------- launch ----------------
extern "C" void kernel_launch(void* const* d_in, const int* in_sizes, int n_in,
                              void* d_out, int out_size, void* d_ws,
                              size_t ws_size, hipStream_t stream) {
  const int B = 4, T = 2048, C = N_EMBD;
  const int M = B * T;  // 8192

  const float* x      = (const float*)d_in[0];
  const float* ln1_g  = (const float*)d_in[1];
  const float* ln1_b  = (const float*)d_in[2];
  const float* attn_w = (const float*)d_in[3];
  const float* attn_b = (const float*)d_in[4];
  const float* proj_w = (const float*)d_in[5];
  const float* proj_b = (const float*)d_in[6];
  const float* ln2_g  = (const float*)d_in[7];
  const float* ln2_b  = (const float*)d_in[8];
  const float* fc_w   = (const float*)d_in[9];
  const float* fc_b   = (const float*)d_in[10];
  const float* fc2_w  = (const float*)d_in[11];
  const float* fc2_b  = (const float*)d_in[12];
  float* out = (float*)d_out;

  char* p = (char*)d_ws;
  size_t off = 0;
  auto take = [&](size_t bytes) -> void* {
    void* q = p + off;
    off += (bytes + 1023) & ~(size_t)1023;
    return q;
  };

  __hip_bfloat16* wqkv  = (__hip_bfloat16*)take((size_t)3 * C * C * 2);
  __hip_bfloat16* wproj = (__hip_bfloat16*)take((size_t)C * C * 2);
  __hip_bfloat16* wfc   = (__hip_bfloat16*)take((size_t)4 * C * C * 2);
  __hip_bfloat16* wfc2  = (__hip_bfloat16*)take((size_t)4 * C * C * 2);
  __hip_bfloat16* hbuf  = (__hip_bfloat16*)take((size_t)M * C * 2);
  __hip_bfloat16* big   = (__hip_bfloat16*)take((size_t)M * 4 * C * 2);
  __hip_bfloat16* ybuf  = (__hip_bfloat16*)take((size_t)M * C * 2);
  float*          x1    = (float*)take((size_t)M * C * 4);

  {
    const int n0 = 3 * C * C, n1 = C * C, n2 = 4 * C * C, n3 = 4 * C * C;
    const int ntot = n0 + n1 + n2 + n3;
    cvt4_kernel<<<(ntot + 255) / 256, 256, 0, stream>>>(
        attn_w, wqkv, proj_w, wproj, fc_w, wfc, fc2_w, wfc2, n0, n1, n2, n3);
  }

  ln_kernel<<<M, 256, 0, stream>>>(x, ln1_g, ln1_b, hbuf);
  gemm256b<0><<<dim3(3 * C / BN3, M / BM3), 512, 0, stream>>>(
      hbuf, wqkv, attn_b, big, M, 3 * C, C);
  attn_mfma<<<dim3(T / 128, B * N_HEADS), 256, 0, stream>>>(big, ybuf, T);
  gemm_bt<2><<<dim3(C / TILE_N, M / TILE_M), 256, 0, stream>>>(
      ybuf, wproj, proj_b, x, nullptr, x1, M, C, C);
  ln_kernel<<<M, 256, 0, stream>>>(x1, ln2_g, ln2_b, hbuf);
  gemm256b<1><<<dim3(4 * C / BN3, M / BM3), 512, 0, stream>>>(
      hbuf, wfc, fc_b, big, M, 4 * C, C);
  gemm_bt<2><<<dim3(C / TILE_N, M / TILE_M), 256, 0, stream>>>(
      big, wfc2, fc2_b, x1, nullptr, out, M, C, 4 * C);
}

// Round 12
// 300.168 us; speedup vs baseline: 1.1524x; 1.0181x over previous
//
#include <hip/hip_runtime.h>
#include <hip/hip_bf16.h>

#define N_EMBD 768
#define N_HEADS 12
#define HEAD_DIM 64

typedef __attribute__((ext_vector_type(4))) float f32x4;
typedef __attribute__((ext_vector_type(8))) short s16x8;

__device__ __forceinline__ float bf2f(unsigned short u) {
  union { unsigned int i; float f; } z;
  z.i = ((unsigned int)u) << 16;
  return z.f;
}

__device__ __forceinline__ void gload_lds16(const void* g, void* l) {
  __builtin_amdgcn_global_load_lds(
      (const __attribute__((address_space(1))) void*)g,
      (__attribute__((address_space(3))) void*)l, 16, 0, 0);
}

__device__ __forceinline__ float gelu_f(float x) {
  const float c = 0.7978845608028654f;
  float u = c * (x + 0.044715f * x * x * x);
  float t = 1.0f - 2.0f / (__expf(2.0f * u) + 1.0f);
  return 0.5f * x * (1.0f + t);
}

// ---------------- weight fp32 -> bf16 (all four in one launch) ----------------
__global__ void cvt4_kernel(const float* __restrict__ s0, __hip_bfloat16* d0,
                            const float* __restrict__ s1, __hip_bfloat16* d1,
                            const float* __restrict__ s2, __hip_bfloat16* d2,
                            const float* __restrict__ s3, __hip_bfloat16* d3,
                            int n0, int n1, int n2, int n3) {
  int i = blockIdx.x * 256 + threadIdx.x;
  if (i < n0) { d0[i] = __float2bfloat16(s0[i]); return; }
  i -= n0;
  if (i < n1) { d1[i] = __float2bfloat16(s1[i]); return; }
  i -= n1;
  if (i < n2) { d2[i] = __float2bfloat16(s2[i]); return; }
  i -= n2;
  if (i < n3) d3[i] = __float2bfloat16(s3[i]);
}

// ---------------- fused LayerNorm: fp32 in -> bf16 out ----------------
__global__ __launch_bounds__(256) void ln_kernel(
    const float* __restrict__ x, const float* __restrict__ g,
    const float* __restrict__ b, __hip_bfloat16* __restrict__ out) {
  __shared__ float red[8];
  const int row = blockIdx.x;
  const int tid = threadIdx.x;
  const float* xr = x + (size_t)row * N_EMBD;
  float v0 = xr[tid], v1 = xr[tid + 256], v2 = xr[tid + 512];
  float s = v0 + v1 + v2;
#pragma unroll
  for (int m = 32; m >= 1; m >>= 1) s += __shfl_xor(s, m);
  if ((tid & 63) == 0) red[tid >> 6] = s;
  __syncthreads();
  float mu = (red[0] + red[1] + red[2] + red[3]) * (1.0f / 768.0f);
  float d0 = v0 - mu, d1 = v1 - mu, d2 = v2 - mu;
  float ss = d0 * d0 + d1 * d1 + d2 * d2;
  __syncthreads();
#pragma unroll
  for (int m = 32; m >= 1; m >>= 1) ss += __shfl_xor(ss, m);
  if ((tid & 63) == 0) red[4 + (tid >> 6)] = ss;
  __syncthreads();
  float var = (red[4] + red[5] + red[6] + red[7]) * (1.0f / 768.0f);
  float rstd = rsqrtf(var + 1e-5f);
  __hip_bfloat16* orow = out + (size_t)row * N_EMBD;
  orow[tid]       = __float2bfloat16(d0 * rstd * g[tid]       + b[tid]);
  orow[tid + 256] = __float2bfloat16(d1 * rstd * g[tid + 256] + b[tid + 256]);
  orow[tid + 512] = __float2bfloat16(d2 * rstd * g[tid + 512] + b[tid + 512]);
}

// ---------------- 128x128 GEMM, counted-vmcnt (ALL four GEMMs this round) ----------------
#define TILE_M 128
#define TILE_N 128
#define TILE_K 32

template <int EPI>
__global__ __launch_bounds__(256) void gemm_bt(
    const __hip_bfloat16* __restrict__ A, const __hip_bfloat16* __restrict__ W,
    const float* __restrict__ bias, const float* __restrict__ resid,
    __hip_bfloat16* __restrict__ outb, float* __restrict__ outf,
    int M, int N, int K) {
  __shared__ __hip_bfloat16 smA[2][TILE_M * TILE_K];
  __shared__ __hip_bfloat16 smB[2][TILE_N * TILE_K];
  const int tid = threadIdx.x;
  const int lane = tid & 63;
  const int wave = tid >> 6;

  const int nbx = gridDim.x;
  const int nwg = nbx * gridDim.y;
  int bid = blockIdx.y * nbx + blockIdx.x;
  if ((nwg & 7) == 0) bid = (bid & 7) * (nwg >> 3) + (bid >> 3);
  const int m0 = (bid / nbx) * TILE_M;
  const int n0 = (bid % nbx) * TILE_N;
  const int wr = wave >> 1, wc = wave & 1;

  f32x4 acc[4][4];
#pragma unroll
  for (int i = 0; i < 4; ++i)
#pragma unroll
    for (int j = 0; j < 4; ++j) acc[i][j] = f32x4{0.f, 0.f, 0.f, 0.f};

  const int ar0 = tid >> 2;
  const int ac0 = (tid & 3) * 8;
  const __hip_bfloat16* Abase0 = A + (size_t)(m0 + ar0) * K + ac0;
  const __hip_bfloat16* Abase1 = A + (size_t)(m0 + 64 + ar0) * K + ac0;
  const __hip_bfloat16* Wbase0 = W + (size_t)(n0 + ar0) * K + ac0;
  const __hip_bfloat16* Wbase1 = W + (size_t)(n0 + 64 + ar0) * K + ac0;

  auto stage = [&](int buf, int k0) {
    gload_lds16(Abase0 + k0, &smA[buf][wave * 512]);
    gload_lds16(Abase1 + k0, &smA[buf][2048 + wave * 512]);
    gload_lds16(Wbase0 + k0, &smB[buf][wave * 512]);
    gload_lds16(Wbase1 + k0, &smB[buf][2048 + wave * 512]);
  };

  const int rA = lane & 15;
  const int ko = (lane >> 4) * 8;
  const int nk = K / TILE_K;

  stage(0, 0);

  int cur = 0;
  for (int t = 0; t < nk; ++t) {
    asm volatile("s_waitcnt vmcnt(0)" ::: "memory");  // tile t landed
    asm volatile("s_barrier" ::: "memory");           // publish t / release t-1
    if (t + 1 < nk) stage(cur ^ 1, (t + 1) * TILE_K); // in flight across next barrier

    s16x8 af[4], bfr[4];
#pragma unroll
    for (int mi = 0; mi < 4; ++mi)
      af[mi] = *(const s16x8*)&smA[cur][(wr * 64 + mi * 16 + rA) * TILE_K + ko];
#pragma unroll
    for (int ni = 0; ni < 4; ++ni)
      bfr[ni] = *(const s16x8*)&smB[cur][(wc * 64 + ni * 16 + rA) * TILE_K + ko];
    __builtin_amdgcn_s_setprio(1);
#pragma unroll
    for (int mi = 0; mi < 4; ++mi)
#pragma unroll
      for (int ni = 0; ni < 4; ++ni)
        acc[mi][ni] = __builtin_amdgcn_mfma_f32_16x16x32_bf16(
            af[mi], bfr[ni], acc[mi][ni], 0, 0, 0);
    __builtin_amdgcn_s_setprio(0);
    cur ^= 1;
  }

  const int crow = (lane >> 4) * 4;
  const int ccol = lane & 15;
#pragma unroll
  for (int mi = 0; mi < 4; ++mi) {
#pragma unroll
    for (int ni = 0; ni < 4; ++ni) {
      const int col = n0 + wc * 64 + ni * 16 + ccol;
      const float bv = bias[col];
#pragma unroll
      for (int j = 0; j < 4; ++j) {
        const int row = m0 + wr * 64 + mi * 16 + crow + j;
        float v = acc[mi][ni][j] + bv;
        const size_t o = (size_t)row * N + col;
        if (EPI == 0) {
          outb[o] = __float2bfloat16(v);
        } else if (EPI == 1) {
          outb[o] = __float2bfloat16(gelu_f(v));
        } else {
          outf[o] = resid[o] + v;
        }
      }
    }
  }
}

// ---------------- MFMA causal flash attention, v4 ----------------
// v3 (paired q-tiles, reg-prefetch, swapped QK^T, T13) + double-buffered
// K/V LDS -> ONE barrier per k-tile: loadKV(t+1); process(buf) x2;
// writeKV(buf^1); sync. Write consumes the loads right before the barrier
// so the implicit vmcnt-drain is free; buffers disjoint per interval.
#define AP 72

__global__ __launch_bounds__(256) void attn_mfma(
    const __hip_bfloat16* __restrict__ qkv, __hip_bfloat16* __restrict__ y,
    int T) {
  __shared__ __hip_bfloat16 ks[2][64 * AP];   // [buf][key][d]
  __shared__ __hip_bfloat16 vt[2][64 * AP];   // [buf][d][key]
  __shared__ __hip_bfloat16 ps[4][16 * AP];   // per-wave P [q][key]
  const int tid = threadIdx.x;
  const int lane = tid & 63;
  const int wave = tid >> 6;
  const int b = blockIdx.y / N_HEADS, h = blockIdx.y % N_HEADS;
  const int nq = T / 64;
  const int qa0 = blockIdx.x * 64;             // early tile
  const int qb0 = (nq - 1 - blockIdx.x) * 64;  // late tile
  const size_t ldq = 3 * N_EMBD;
  const __hip_bfloat16* qb_ = qkv + (size_t)b * T * ldq + h * HEAD_DIM;
  const __hip_bfloat16* kb = qb_ + N_EMBD;
  const __hip_bfloat16* vb = qb_ + 2 * N_EMBD;

  const int fr = lane & 15;          // q-row owned by this lane (swapped QK)
  const int fo = (lane >> 4) * 8;    // fragment k-offset
  const int crow = (lane >> 4) * 4;  // C/D row base (= key sub-block here)

  const float qs = 0.125f * 1.44269504f;
  auto loadq = [&](int qrow, int o) -> s16x8 {
    s16x8 v = *(const s16x8*)(qb_ + (size_t)qrow * ldq + o);
    s16x8 r;
#pragma unroll
    for (int i = 0; i < 8; ++i) {
      float f = bf2f((unsigned short)v[i]) * qs;
      __hip_bfloat16 hb = __float2bfloat16(f);
      r[i] = *reinterpret_cast<short*>(&hb);
    }
    return r;
  };
  s16x8 qfa0 = loadq(qa0 + wave * 16 + fr, fo);
  s16x8 qfa1 = loadq(qa0 + wave * 16 + fr, fo + 32);
  s16x8 qfb0 = loadq(qb0 + wave * 16 + fr, fo);
  s16x8 qfb1 = loadq(qb0 + wave * 16 + fr, fo + 32);

  f32x4 oa[4], ob[4];
#pragma unroll
  for (int j = 0; j < 4; ++j) {
    oa[j] = f32x4{0.f, 0.f, 0.f, 0.f};
    ob[j] = f32x4{0.f, 0.f, 0.f, 0.f};
  }
  float m_a = -1e30f, l_a = 0.f, m_b = -1e30f, l_b = 0.f;

  // reg-prefetch staging (KVBLK=64)
  s16x8 kr0, kr1, vr0, vr1;
  const int krow0 = tid >> 3;
  const int kcol = (tid & 7) * 8;
  const int vkey = 2 * (lane & 31);
  const int vd0 = wave * 16 + (lane >> 5) * 8;

  auto loadKV = [&](int kt) {
    kr0 = *(const s16x8*)(kb + (size_t)(kt + krow0) * ldq + kcol);
    kr1 = *(const s16x8*)(kb + (size_t)(kt + 32 + krow0) * ldq + kcol);
    vr0 = *(const s16x8*)(vb + (size_t)(kt + vkey) * ldq + vd0);
    vr1 = *(const s16x8*)(vb + (size_t)(kt + vkey + 1) * ldq + vd0);
  };
  auto writeKV = [&](int bufi) {
    *(s16x8*)&ks[bufi][krow0 * AP + kcol] = kr0;
    *(s16x8*)&ks[bufi][(32 + krow0) * AP + kcol] = kr1;
#pragma unroll
    for (int i = 0; i < 8; ++i) {
      unsigned u = (unsigned short)vr0[i] | ((unsigned)(unsigned short)vr1[i] << 16);
      *(unsigned*)&vt[bufi][(vd0 + i) * AP + vkey] = u;
    }
  };

  auto process = [&](int bufi, const s16x8& q0f, const s16x8& q1f,
                     f32x4 (&o)[4], float& m_, float& l_, int tq0, bool diag,
                     int kt) {
    f32x4 sv[4];
#pragma unroll
    for (int sub = 0; sub < 4; ++sub) {
      s16x8 k0 = *(const s16x8*)&ks[bufi][(sub * 16 + fr) * AP + fo];
      s16x8 k1 = *(const s16x8*)&ks[bufi][(sub * 16 + fr) * AP + 32 + fo];
      f32x4 acc = f32x4{0.f, 0.f, 0.f, 0.f};
      acc = __builtin_amdgcn_mfma_f32_16x16x32_bf16(k0, q0f, acc, 0, 0, 0);
      acc = __builtin_amdgcn_mfma_f32_16x16x32_bf16(k1, q1f, acc, 0, 0, 0);
      sv[sub] = acc;
    }
    const int qg = tq0 + wave * 16 + fr;
    if (diag) {
#pragma unroll
      for (int sub = 0; sub < 4; ++sub)
#pragma unroll
        for (int j = 0; j < 4; ++j)
          if (kt + sub * 16 + crow + j > qg) sv[sub][j] = -1e30f;
    }
    float t = fmaxf(fmaxf(sv[0][0], sv[0][1]), fmaxf(sv[0][2], sv[0][3]));
#pragma unroll
    for (int sub = 1; sub < 4; ++sub)
      t = fmaxf(t, fmaxf(fmaxf(sv[sub][0], sv[sub][1]),
                         fmaxf(sv[sub][2], sv[sub][3])));
    t = fmaxf(t, __shfl_xor(t, 16));
    t = fmaxf(t, __shfl_xor(t, 32));
    const bool resc = t > m_ + 8.0f;  // T13 defer-max
    const float corr = resc ? exp2f(m_ - t) : 1.0f;
    if (resc) m_ = t;
    float rs = 0.f;
#pragma unroll
    for (int sub = 0; sub < 4; ++sub) {
#pragma unroll
      for (int j = 0; j < 4; ++j) {
        float p = exp2f(sv[sub][j] - m_);
        rs += p;
        ps[wave][fr * AP + sub * 16 + crow + j] = __float2bfloat16(p);
      }
    }
    rs += __shfl_xor(rs, 16);
    rs += __shfl_xor(rs, 32);
    l_ = l_ * corr + rs;
    if (__any(resc)) {
#pragma unroll
      for (int j = 0; j < 4; ++j) {
        const float cj = __shfl(corr, (lane & 0x30) | (crow + j));
#pragma unroll
        for (int ds = 0; ds < 4; ++ds) o[ds][j] *= cj;
      }
    }
    s16x8 pf0 = *(const s16x8*)&ps[wave][fr * AP + fo];
    s16x8 pf1 = *(const s16x8*)&ps[wave][fr * AP + 32 + fo];
#pragma unroll
    for (int ds = 0; ds < 4; ++ds) {
      s16x8 v0 = *(const s16x8*)&vt[bufi][(ds * 16 + fr) * AP + fo];
      s16x8 v1 = *(const s16x8*)&vt[bufi][(ds * 16 + fr) * AP + 32 + fo];
      o[ds] = __builtin_amdgcn_mfma_f32_16x16x32_bf16(pf0, v0, o[ds], 0, 0, 0);
      o[ds] = __builtin_amdgcn_mfma_f32_16x16x32_bf16(pf1, v1, o[ds], 0, 0, 0);
    }
  };

  loadKV(0);
  writeKV(0);
  __syncthreads();   // tile 0 published
  int cur = 0;
  for (int kt = 0; kt <= qb0; kt += 64) {
    const bool hasnext = (kt + 64 <= qb0);
    if (hasnext) loadKV(kt + 64);  // global->reg, flies under process
    if (kt <= qa0)
      process(cur, qfa0, qfa1, oa, m_a, l_a, qa0, kt == qa0, kt);
    process(cur, qfb0, qfb1, ob, m_b, l_b, qb0, kt == qb0, kt);
    if (hasnext) writeKV(cur ^ 1); // disjoint buffer; consumes the loads
    __syncthreads();               // one barrier per tile
    cur ^= 1;
  }

#pragma unroll
  for (int j = 0; j < 4; ++j) {
    const float la_j = __shfl(l_a, (lane & 0x30) | (crow + j));
    const float lb_j = __shfl(l_b, (lane & 0x30) | (crow + j));
    const float inva = 1.0f / la_j;
    const float invb = 1.0f / lb_j;
    __hip_bfloat16* ya =
        y + (size_t)(b * T + qa0 + wave * 16 + crow + j) * N_EMBD + h * HEAD_DIM;
    __hip_bfloat16* yb =
        y + (size_t)(b * T + qb0 + wave * 16 + crow + j) * N_EMBD + h * HEAD_DIM;
#pragma unroll
    for (int ds = 0; ds < 4; ++ds) {
      ya[ds * 16 + fr] = __float2bfloat16(oa[ds][j] * inva);
      yb[ds * 16 + fr] = __float2bfloat16(ob[ds][j] * invb);
    }
  }
}

// ---------------- launch ----------------
extern "C" void kernel_launch(void* const* d_in, const int* in_sizes, int n_in,
                              void* d_out, int out_size, void* d_ws,
                              size_t ws_size, hipStream_t stream) {
  const int B = 4, T = 2048, C = N_EMBD;
  const int M = B * T;  // 8192

  const float* x      = (const float*)d_in[0];
  const float* ln1_g  = (const float*)d_in[1];
  const float* ln1_b  = (const float*)d_in[2];
  const float* attn_w = (const float*)d_in[3];
  const float* attn_b = (const float*)d_in[4];
  const float* proj_w = (const float*)d_in[5];
  const float* proj_b = (const float*)d_in[6];
  const float* ln2_g  = (const float*)d_in[7];
  const float* ln2_b  = (const float*)d_in[8];
  const float* fc_w   = (const float*)d_in[9];
  const float* fc_b   = (const float*)d_in[10];
  const float* fc2_w  = (const float*)d_in[11];
  const float* fc2_b  = (const float*)d_in[12];
  float* out = (float*)d_out;

  char* p = (char*)d_ws;
  size_t off = 0;
  auto take = [&](size_t bytes) -> void* {
    void* q = p + off;
    off += (bytes + 1023) & ~(size_t)1023;
    return q;
  };

  __hip_bfloat16* wqkv  = (__hip_bfloat16*)take((size_t)3 * C * C * 2);
  __hip_bfloat16* wproj = (__hip_bfloat16*)take((size_t)C * C * 2);
  __hip_bfloat16* wfc   = (__hip_bfloat16*)take((size_t)4 * C * C * 2);
  __hip_bfloat16* wfc2  = (__hip_bfloat16*)take((size_t)4 * C * C * 2);
  __hip_bfloat16* hbuf  = (__hip_bfloat16*)take((size_t)M * C * 2);
  __hip_bfloat16* big   = (__hip_bfloat16*)take((size_t)M * 4 * C * 2);
  __hip_bfloat16* ybuf  = (__hip_bfloat16*)take((size_t)M * C * 2);
  float*          x1    = (float*)take((size_t)M * C * 4);

  {
    const int n0 = 3 * C * C, n1 = C * C, n2 = 4 * C * C, n3 = 4 * C * C;
    const int ntot = n0 + n1 + n2 + n3;
    cvt4_kernel<<<(ntot + 255) / 256, 256, 0, stream>>>(
        attn_w, wqkv, proj_w, wproj, fc_w, wfc, fc2_w, wfc2, n0, n1, n2, n3);
  }

  ln_kernel<<<M, 256, 0, stream>>>(x, ln1_g, ln1_b, hbuf);
  gemm_bt<0><<<dim3(3 * C / TILE_N, M / TILE_M), 256, 0, stream>>>(
      hbuf, wqkv, attn_b, nullptr, big, nullptr, M, 3 * C, C);
  attn_mfma<<<dim3(T / 128, B * N_HEADS), 256, 0, stream>>>(big, ybuf, T);
  gemm_bt<2><<<dim3(C / TILE_N, M / TILE_M), 256, 0, stream>>>(
      ybuf, wproj, proj_b, x, nullptr, x1, M, C, C);
  ln_kernel<<<M, 256, 0, stream>>>(x1, ln2_g, ln2_b, hbuf);
  gemm_bt<1><<<dim3(4 * C / TILE_N, M / TILE_M), 256, 0, stream>>>(
      hbuf, wfc, fc_b, nullptr, big, nullptr, M, 4 * C, C);
  gemm_bt<2><<<dim3(C / TILE_N, M / TILE_M), 256, 0, stream>>>(
      big, wfc2, fc2_b, x1, nullptr, out, M, C, 4 * C);
}

// Round 13
// 294.941 us; speedup vs baseline: 1.1728x; 1.0177x over previous
//
#include <hip/hip_runtime.h>
#include <hip/hip_bf16.h>

#define N_EMBD 768
#define N_HEADS 12
#define HEAD_DIM 64

typedef __attribute__((ext_vector_type(4))) float f32x4;
typedef __attribute__((ext_vector_type(8))) short s16x8;

__device__ __forceinline__ float bf2f(unsigned short u) {
  union { unsigned int i; float f; } z;
  z.i = ((unsigned int)u) << 16;
  return z.f;
}

__device__ __forceinline__ void gload_lds16(const void* g, void* l) {
  __builtin_amdgcn_global_load_lds(
      (const __attribute__((address_space(1))) void*)g,
      (__attribute__((address_space(3))) void*)l, 16, 0, 0);
}

__device__ __forceinline__ float gelu_f(float x) {
  const float c = 0.7978845608028654f;
  float u = c * (x + 0.044715f * x * x * x);
  float t = 1.0f - 2.0f / (__expf(2.0f * u) + 1.0f);
  return 0.5f * x * (1.0f + t);
}

// ---------------- weight fp32 -> bf16 (all four in one launch) ----------------
__global__ void cvt4_kernel(const float* __restrict__ s0, __hip_bfloat16* d0,
                            const float* __restrict__ s1, __hip_bfloat16* d1,
                            const float* __restrict__ s2, __hip_bfloat16* d2,
                            const float* __restrict__ s3, __hip_bfloat16* d3,
                            int n0, int n1, int n2, int n3) {
  int i = blockIdx.x * 256 + threadIdx.x;
  if (i < n0) { d0[i] = __float2bfloat16(s0[i]); return; }
  i -= n0;
  if (i < n1) { d1[i] = __float2bfloat16(s1[i]); return; }
  i -= n1;
  if (i < n2) { d2[i] = __float2bfloat16(s2[i]); return; }
  i -= n2;
  if (i < n3) d3[i] = __float2bfloat16(s3[i]);
}

// ---------------- fused LayerNorm: fp32 in -> bf16 out ----------------
__global__ __launch_bounds__(256) void ln_kernel(
    const float* __restrict__ x, const float* __restrict__ g,
    const float* __restrict__ b, __hip_bfloat16* __restrict__ out) {
  __shared__ float red[8];
  const int row = blockIdx.x;
  const int tid = threadIdx.x;
  const float* xr = x + (size_t)row * N_EMBD;
  float v0 = xr[tid], v1 = xr[tid + 256], v2 = xr[tid + 512];
  float s = v0 + v1 + v2;
#pragma unroll
  for (int m = 32; m >= 1; m >>= 1) s += __shfl_xor(s, m);
  if ((tid & 63) == 0) red[tid >> 6] = s;
  __syncthreads();
  float mu = (red[0] + red[1] + red[2] + red[3]) * (1.0f / 768.0f);
  float d0 = v0 - mu, d1 = v1 - mu, d2 = v2 - mu;
  float ss = d0 * d0 + d1 * d1 + d2 * d2;
  __syncthreads();
#pragma unroll
  for (int m = 32; m >= 1; m >>= 1) ss += __shfl_xor(ss, m);
  if ((tid & 63) == 0) red[4 + (tid >> 6)] = ss;
  __syncthreads();
  float var = (red[4] + red[5] + red[6] + red[7]) * (1.0f / 768.0f);
  float rstd = rsqrtf(var + 1e-5f);
  __hip_bfloat16* orow = out + (size_t)row * N_EMBD;
  orow[tid]       = __float2bfloat16(d0 * rstd * g[tid]       + b[tid]);
  orow[tid + 256] = __float2bfloat16(d1 * rstd * g[tid + 256] + b[tid + 256]);
  orow[tid + 512] = __float2bfloat16(d2 * rstd * g[tid + 512] + b[tid + 512]);
}

// ---------------- 128x128 GEMM, counted-vmcnt + XOR bank swizzle ----------------
// LDS granule (row, g) holds global col-granule g^((row>>1)&3): staging
// pre-swizzles the SOURCE col (dest stays linear for global_load_lds),
// fragment reads apply the same XOR -> 16 lanes spread over 8 banks
// (2-way aliasing = free) instead of 8-way conflict.
#define TILE_M 128
#define TILE_N 128
#define TILE_K 32

template <int EPI>
__global__ __launch_bounds__(256) void gemm_bt(
    const __hip_bfloat16* __restrict__ A, const __hip_bfloat16* __restrict__ W,
    const float* __restrict__ bias, const float* __restrict__ resid,
    __hip_bfloat16* __restrict__ outb, float* __restrict__ outf,
    int M, int N, int K) {
  __shared__ __hip_bfloat16 smA[2][TILE_M * TILE_K];
  __shared__ __hip_bfloat16 smB[2][TILE_N * TILE_K];
  const int tid = threadIdx.x;
  const int lane = tid & 63;
  const int wave = tid >> 6;

  const int nbx = gridDim.x;
  const int nwg = nbx * gridDim.y;
  int bid = blockIdx.y * nbx + blockIdx.x;
  if ((nwg & 7) == 0) bid = (bid & 7) * (nwg >> 3) + (bid >> 3);
  const int m0 = (bid / nbx) * TILE_M;
  const int n0 = (bid % nbx) * TILE_N;
  const int wr = wave >> 1, wc = wave & 1;

  f32x4 acc[4][4];
#pragma unroll
  for (int i = 0; i < 4; ++i)
#pragma unroll
    for (int j = 0; j < 4; ++j) acc[i][j] = f32x4{0.f, 0.f, 0.f, 0.f};

  // staging: thread tid owns granule (row = tid>>2, g = tid&3) and row+64.
  // source col granule = g ^ ((row>>1)&3)  [same XOR for row+64: 64>>1 % 4 == 0]
  const int ar0 = tid >> 2;
  const int ac0 = (((tid & 3) ^ ((ar0 >> 1) & 3))) * 8;
  const __hip_bfloat16* Abase0 = A + (size_t)(m0 + ar0) * K + ac0;
  const __hip_bfloat16* Abase1 = A + (size_t)(m0 + 64 + ar0) * K + ac0;
  const __hip_bfloat16* Wbase0 = W + (size_t)(n0 + ar0) * K + ac0;
  const __hip_bfloat16* Wbase1 = W + (size_t)(n0 + 64 + ar0) * K + ac0;

  auto stage = [&](int buf, int k0) {
    gload_lds16(Abase0 + k0, &smA[buf][wave * 512]);
    gload_lds16(Abase1 + k0, &smA[buf][2048 + wave * 512]);
    gload_lds16(Wbase0 + k0, &smB[buf][wave * 512]);
    gload_lds16(Wbase1 + k0, &smB[buf][2048 + wave * 512]);
  };

  const int rA = lane & 15;
  const int fq = lane >> 4;  // global k-granule wanted
  const int nk = K / TILE_K;

  stage(0, 0);

  int cur = 0;
  for (int t = 0; t < nk; ++t) {
    asm volatile("s_waitcnt vmcnt(0)" ::: "memory");  // tile t landed
    asm volatile("s_barrier" ::: "memory");           // publish t / release t-1
    if (t + 1 < nk) stage(cur ^ 1, (t + 1) * TILE_K); // in flight across next barrier

    s16x8 af[4], bfr[4];
#pragma unroll
    for (int mi = 0; mi < 4; ++mi) {
      const int row = wr * 64 + mi * 16 + rA;
      const int g = fq ^ ((row >> 1) & 3);
      af[mi] = *(const s16x8*)&smA[cur][row * TILE_K + g * 8];
    }
#pragma unroll
    for (int ni = 0; ni < 4; ++ni) {
      const int row = wc * 64 + ni * 16 + rA;
      const int g = fq ^ ((row >> 1) & 3);
      bfr[ni] = *(const s16x8*)&smB[cur][row * TILE_K + g * 8];
    }
    __builtin_amdgcn_s_setprio(1);
#pragma unroll
    for (int mi = 0; mi < 4; ++mi)
#pragma unroll
      for (int ni = 0; ni < 4; ++ni)
        acc[mi][ni] = __builtin_amdgcn_mfma_f32_16x16x32_bf16(
            af[mi], bfr[ni], acc[mi][ni], 0, 0, 0);
    __builtin_amdgcn_s_setprio(0);
    cur ^= 1;
  }

  const int crow = (lane >> 4) * 4;
  const int ccol = lane & 15;
#pragma unroll
  for (int mi = 0; mi < 4; ++mi) {
#pragma unroll
    for (int ni = 0; ni < 4; ++ni) {
      const int col = n0 + wc * 64 + ni * 16 + ccol;
      const float bv = bias[col];
#pragma unroll
      for (int j = 0; j < 4; ++j) {
        const int row = m0 + wr * 64 + mi * 16 + crow + j;
        float v = acc[mi][ni][j] + bv;
        const size_t o = (size_t)row * N + col;
        if (EPI == 0) {
          outb[o] = __float2bfloat16(v);
        } else if (EPI == 1) {
          outb[o] = __float2bfloat16(gelu_f(v));
        } else {
          outf[o] = resid[o] + v;
        }
      }
    }
  }
}

// ---------------- MFMA causal flash attention, v4 (R12-verified) ----------------
#define AP 72

__global__ __launch_bounds__(256) void attn_mfma(
    const __hip_bfloat16* __restrict__ qkv, __hip_bfloat16* __restrict__ y,
    int T) {
  __shared__ __hip_bfloat16 ks[2][64 * AP];   // [buf][key][d]
  __shared__ __hip_bfloat16 vt[2][64 * AP];   // [buf][d][key]
  __shared__ __hip_bfloat16 ps[4][16 * AP];   // per-wave P [q][key]
  const int tid = threadIdx.x;
  const int lane = tid & 63;
  const int wave = tid >> 6;
  const int b = blockIdx.y / N_HEADS, h = blockIdx.y % N_HEADS;
  const int nq = T / 64;
  const int qa0 = blockIdx.x * 64;
  const int qb0 = (nq - 1 - blockIdx.x) * 64;
  const size_t ldq = 3 * N_EMBD;
  const __hip_bfloat16* qb_ = qkv + (size_t)b * T * ldq + h * HEAD_DIM;
  const __hip_bfloat16* kb = qb_ + N_EMBD;
  const __hip_bfloat16* vb = qb_ + 2 * N_EMBD;

  const int fr = lane & 15;
  const int fo = (lane >> 4) * 8;
  const int crow = (lane >> 4) * 4;

  const float qs = 0.125f * 1.44269504f;
  auto loadq = [&](int qrow, int o) -> s16x8 {
    s16x8 v = *(const s16x8*)(qb_ + (size_t)qrow * ldq + o);
    s16x8 r;
#pragma unroll
    for (int i = 0; i < 8; ++i) {
      float f = bf2f((unsigned short)v[i]) * qs;
      __hip_bfloat16 hb = __float2bfloat16(f);
      r[i] = *reinterpret_cast<short*>(&hb);
    }
    return r;
  };
  s16x8 qfa0 = loadq(qa0 + wave * 16 + fr, fo);
  s16x8 qfa1 = loadq(qa0 + wave * 16 + fr, fo + 32);
  s16x8 qfb0 = loadq(qb0 + wave * 16 + fr, fo);
  s16x8 qfb1 = loadq(qb0 + wave * 16 + fr, fo + 32);

  f32x4 oa[4], ob[4];
#pragma unroll
  for (int j = 0; j < 4; ++j) {
    oa[j] = f32x4{0.f, 0.f, 0.f, 0.f};
    ob[j] = f32x4{0.f, 0.f, 0.f, 0.f};
  }
  float m_a = -1e30f, l_a = 0.f, m_b = -1e30f, l_b = 0.f;

  s16x8 kr0, kr1, vr0, vr1;
  const int krow0 = tid >> 3;
  const int kcol = (tid & 7) * 8;
  const int vkey = 2 * (lane & 31);
  const int vd0 = wave * 16 + (lane >> 5) * 8;

  auto loadKV = [&](int kt) {
    kr0 = *(const s16x8*)(kb + (size_t)(kt + krow0) * ldq + kcol);
    kr1 = *(const s16x8*)(kb + (size_t)(kt + 32 + krow0) * ldq + kcol);
    vr0 = *(const s16x8*)(vb + (size_t)(kt + vkey) * ldq + vd0);
    vr1 = *(const s16x8*)(vb + (size_t)(kt + vkey + 1) * ldq + vd0);
  };
  auto writeKV = [&](int bufi) {
    *(s16x8*)&ks[bufi][krow0 * AP + kcol] = kr0;
    *(s16x8*)&ks[bufi][(32 + krow0) * AP + kcol] = kr1;
#pragma unroll
    for (int i = 0; i < 8; ++i) {
      unsigned u = (unsigned short)vr0[i] | ((unsigned)(unsigned short)vr1[i] << 16);
      *(unsigned*)&vt[bufi][(vd0 + i) * AP + vkey] = u;
    }
  };

  auto process = [&](int bufi, const s16x8& q0f, const s16x8& q1f,
                     f32x4 (&o)[4], float& m_, float& l_, int tq0, bool diag,
                     int kt) {
    f32x4 sv[4];
#pragma unroll
    for (int sub = 0; sub < 4; ++sub) {
      s16x8 k0 = *(const s16x8*)&ks[bufi][(sub * 16 + fr) * AP + fo];
      s16x8 k1 = *(const s16x8*)&ks[bufi][(sub * 16 + fr) * AP + 32 + fo];
      f32x4 acc = f32x4{0.f, 0.f, 0.f, 0.f};
      acc = __builtin_amdgcn_mfma_f32_16x16x32_bf16(k0, q0f, acc, 0, 0, 0);
      acc = __builtin_amdgcn_mfma_f32_16x16x32_bf16(k1, q1f, acc, 0, 0, 0);
      sv[sub] = acc;
    }
    const int qg = tq0 + wave * 16 + fr;
    if (diag) {
#pragma unroll
      for (int sub = 0; sub < 4; ++sub)
#pragma unroll
        for (int j = 0; j < 4; ++j)
          if (kt + sub * 16 + crow + j > qg) sv[sub][j] = -1e30f;
    }
    float t = fmaxf(fmaxf(sv[0][0], sv[0][1]), fmaxf(sv[0][2], sv[0][3]));
#pragma unroll
    for (int sub = 1; sub < 4; ++sub)
      t = fmaxf(t, fmaxf(fmaxf(sv[sub][0], sv[sub][1]),
                         fmaxf(sv[sub][2], sv[sub][3])));
    t = fmaxf(t, __shfl_xor(t, 16));
    t = fmaxf(t, __shfl_xor(t, 32));
    const bool resc = t > m_ + 8.0f;  // T13 defer-max
    const float corr = resc ? exp2f(m_ - t) : 1.0f;
    if (resc) m_ = t;
    float rs = 0.f;
#pragma unroll
    for (int sub = 0; sub < 4; ++sub) {
#pragma unroll
      for (int j = 0; j < 4; ++j) {
        float p = exp2f(sv[sub][j] - m_);
        rs += p;
        ps[wave][fr * AP + sub * 16 + crow + j] = __float2bfloat16(p);
      }
    }
    rs += __shfl_xor(rs, 16);
    rs += __shfl_xor(rs, 32);
    l_ = l_ * corr + rs;
    if (__any(resc)) {
#pragma unroll
      for (int j = 0; j < 4; ++j) {
        const float cj = __shfl(corr, (lane & 0x30) | (crow + j));
#pragma unroll
        for (int ds = 0; ds < 4; ++ds) o[ds][j] *= cj;
      }
    }
    s16x8 pf0 = *(const s16x8*)&ps[wave][fr * AP + fo];
    s16x8 pf1 = *(const s16x8*)&ps[wave][fr * AP + 32 + fo];
#pragma unroll
    for (int ds = 0; ds < 4; ++ds) {
      s16x8 v0 = *(const s16x8*)&vt[bufi][(ds * 16 + fr) * AP + fo];
      s16x8 v1 = *(const s16x8*)&vt[bufi][(ds * 16 + fr) * AP + 32 + fo];
      o[ds] = __builtin_amdgcn_mfma_f32_16x16x32_bf16(pf0, v0, o[ds], 0, 0, 0);
      o[ds] = __builtin_amdgcn_mfma_f32_16x16x32_bf16(pf1, v1, o[ds], 0, 0, 0);
    }
  };

  loadKV(0);
  writeKV(0);
  __syncthreads();
  int cur = 0;
  for (int kt = 0; kt <= qb0; kt += 64) {
    const bool hasnext = (kt + 64 <= qb0);
    if (hasnext) loadKV(kt + 64);
    if (kt <= qa0)
      process(cur, qfa0, qfa1, oa, m_a, l_a, qa0, kt == qa0, kt);
    process(cur, qfb0, qfb1, ob, m_b, l_b, qb0, kt == qb0, kt);
    if (hasnext) writeKV(cur ^ 1);
    __syncthreads();
    cur ^= 1;
  }

#pragma unroll
  for (int j = 0; j < 4; ++j) {
    const float la_j = __shfl(l_a, (lane & 0x30) | (crow + j));
    const float lb_j = __shfl(l_b, (lane & 0x30) | (crow + j));
    const float inva = 1.0f / la_j;
    const float invb = 1.0f / lb_j;
    __hip_bfloat16* ya =
        y + (size_t)(b * T + qa0 + wave * 16 + crow + j) * N_EMBD + h * HEAD_DIM;
    __hip_bfloat16* yb =
        y + (size_t)(b * T + qb0 + wave * 16 + crow + j) * N_EMBD + h * HEAD_DIM;
#pragma unroll
    for (int ds = 0; ds < 4; ++ds) {
      ya[ds * 16 + fr] = __float2bfloat16(oa[ds][j] * inva);
      yb[ds * 16 + fr] = __float2bfloat16(ob[ds][j] * invb);
    }
  }
}

// ---------------- launch ----------------
extern "C" void kernel_launch(void* const* d_in, const int* in_sizes, int n_in,
                              void* d_out, int out_size, void* d_ws,
                              size_t ws_size, hipStream_t stream) {
  const int B = 4, T = 2048, C = N_EMBD;
  const int M = B * T;  // 8192

  const float* x      = (const float*)d_in[0];
  const float* ln1_g  = (const float*)d_in[1];
  const float* ln1_b  = (const float*)d_in[2];
  const float* attn_w = (const float*)d_in[3];
  const float* attn_b = (const float*)d_in[4];
  const float* proj_w = (const float*)d_in[5];
  const float* proj_b = (const float*)d_in[6];
  const float* ln2_g  = (const float*)d_in[7];
  const float* ln2_b  = (const float*)d_in[8];
  const float* fc_w   = (const float*)d_in[9];
  const float* fc_b   = (const float*)d_in[10];
  const float* fc2_w  = (const float*)d_in[11];
  const float* fc2_b  = (const float*)d_in[12];
  float* out = (float*)d_out;

  char* p = (char*)d_ws;
  size_t off = 0;
  auto take = [&](size_t bytes) -> void* {
    void* q = p + off;
    off += (bytes + 1023) & ~(size_t)1023;
    return q;
  };

  __hip_bfloat16* wqkv  = (__hip_bfloat16*)take((size_t)3 * C * C * 2);
  __hip_bfloat16* wproj = (__hip_bfloat16*)take((size_t)C * C * 2);
  __hip_bfloat16* wfc   = (__hip_bfloat16*)take((size_t)4 * C * C * 2);
  __hip_bfloat16* wfc2  = (__hip_bfloat16*)take((size_t)4 * C * C * 2);
  __hip_bfloat16* hbuf  = (__hip_bfloat16*)take((size_t)M * C * 2);
  __hip_bfloat16* big   = (__hip_bfloat16*)take((size_t)M * 4 * C * 2);
  __hip_bfloat16* ybuf  = (__hip_bfloat16*)take((size_t)M * C * 2);
  float*          x1    = (float*)take((size_t)M * C * 4);

  {
    const int n0 = 3 * C * C, n1 = C * C, n2 = 4 * C * C, n3 = 4 * C * C;
    const int ntot = n0 + n1 + n2 + n3;
    cvt4_kernel<<<(ntot + 255) / 256, 256, 0, stream>>>(
        attn_w, wqkv, proj_w, wproj, fc_w, wfc, fc2_w, wfc2, n0, n1, n2, n3);
  }

  ln_kernel<<<M, 256, 0, stream>>>(x, ln1_g, ln1_b, hbuf);
  gemm_bt<0><<<dim3(3 * C / TILE_N, M / TILE_M), 256, 0, stream>>>(
      hbuf, wqkv, attn_b, nullptr, big, nullptr, M, 3 * C, C);
  attn_mfma<<<dim3(T / 128, B * N_HEADS), 256, 0, stream>>>(big, ybuf, T);
  gemm_bt<2><<<dim3(C / TILE_N, M / TILE_M), 256, 0, stream>>>(
      ybuf, wproj, proj_b, x, nullptr, x1, M, C, C);
  ln_kernel<<<M, 256, 0, stream>>>(x1, ln2_g, ln2_b, hbuf);
  gemm_bt<1><<<dim3(4 * C / TILE_N, M / TILE_M), 256, 0, stream>>>(
      hbuf, wfc, fc_b, nullptr, big, nullptr, M, 4 * C, C);
  gemm_bt<2><<<dim3(C / TILE_N, M / TILE_M), 256, 0, stream>>>(
      big, wfc2, fc2_b, x1, nullptr, out, M, C, 4 * C);
}